// Round 4
// baseline (227.610 us; speedup 1.0000x reference)
//
#include <hip/hip_runtime.h>

// ScRRAMBLe capsule layer, R4: transform rebuilt on the global_load_lds DMA
// path (m97 GEMM staging pattern) with double-buffered 16 KB k-planes.
//
// R3 post-mortem: occupancy x4 (R2) and 16 hoisted loads/lane (R3) both ~nil
// -> burst loads through the L1/VGPR return path cap at ~2 TB/s. The DMA
// direct-to-LDS path keeps 16 KB/block continuously in flight (~80 KB/CU at
// 5 resident blocks) while waves compute from LDS.

typedef float f4 __attribute__((ext_vector_type(4)));

#define NCH 8   // ij chunks for routing kernel (xr partials: NCH*512*256 floats)

// ---------------- Kernel A: routing einsum ---------------------------------
// grid (128 i-quads, NCH); block 256.
__global__ __launch_bounds__(256) void route_kernel(
    const float* __restrict__ x,
    const float* __restrict__ Ci,
    float* __restrict__ xr_part)
{
    const int iq  = blockIdx.x;
    const int c   = blockIdx.y;
    const int t   = threadIdx.x;
    const int il  = t >> 6;
    const int g   = (t >> 4) & 3;
    const int mq4 = t & 15;
    const int i   = (iq << 2) + il;

    const f4* __restrict__ Ci4 = (const f4*)Ci;
    const f4* __restrict__ x4  = (const f4*)x;

    __shared__ f4 part[1024];

    f4 a0 = {0.f,0.f,0.f,0.f};
    f4 a1 = {0.f,0.f,0.f,0.f};
    f4 a2 = {0.f,0.f,0.f,0.f};
    f4 a3 = {0.f,0.f,0.f,0.f};

    const int ijpc = 2048 / NCH;      // 256
    const int sub  = ijpc >> 2;       // 64 per g-subgroup
    const int base = c * ijpc + g * sub;
    #pragma unroll 4
    for (int it = 0; it < sub; ++it) {
        const int ij = base + it;
        const f4 c4 = Ci4[ij * 512 + i];      // Ci[ij, i, 0:4]
        const f4 xv = x4[(ij << 4) + mq4];    // x[ij, 4*mq4 .. +3]
        a0 += c4.x * xv;
        a1 += c4.y * xv;
        a2 += c4.z * xv;
        a3 += c4.w * xv;
    }

    const int pb = ((g << 2) + il) << 2;
    part[(pb + 0) * 16 + mq4] = a0;
    part[(pb + 1) * 16 + mq4] = a1;
    part[(pb + 2) * 16 + mq4] = a2;
    part[(pb + 3) * 16 + mq4] = a3;
    __syncthreads();

    const int il2 = t >> 6;
    const int r   = (t >> 4) & 3;
    const int mm  = t & 15;
    f4 s = {0.f,0.f,0.f,0.f};
    #pragma unroll
    for (int gg = 0; gg < 4; ++gg)
        s += part[(((gg << 2) + il2) * 4 + r) * 16 + mm];

    f4* __restrict__ xp4 = (f4*)xr_part;
    xp4[(c * 512 + (iq << 2) + il2) * 64 + r * 16 + mm] = s;
}

// ---------------- Kernel B: per-capsule transform, DMA-staged --------------
__device__ __forceinline__ void gload_lds16(const float* g, float* l) {
    __builtin_amdgcn_global_load_lds(
        (const __attribute__((address_space(1))) unsigned int*)g,
        (__attribute__((address_space(3))) unsigned int*)l,
        16, 0, 0);
}

// grid 2048 = (i*4+j); block 256 = 4 waves; wave w owns l in [w*16, w*16+16).
// LDS: 2 x 16 KB k-plane buffers, double-buffered over k=0..3.
__global__ __launch_bounds__(256) void transform_kernel(
    const float* __restrict__ Wi,
    const float* __restrict__ xr_part,
    float* __restrict__ y)
{
    __shared__ float lds[2][4096];   // 32 KB

    const int b    = blockIdx.x;
    const int i    = b >> 2;
    const int t    = threadIdx.x;
    const int lane = t & 63;
    const int w    = t >> 6;
    const int lq   = lane >> 4;
    const int m16  = lane & 15;

    const float* Wb = Wi + (size_t)b * 16384;   // this slice: [k][l][m] 4x64x64

    // stage plane 0 -> buf0 (4 x 16B per thread, lane-contiguous per wave)
    #pragma unroll
    for (int p = 0; p < 4; ++p)
        gload_lds16(Wb + 0 * 4096 + p * 1024 + t * 4, &lds[0][p * 1024 + t * 4]);

    // xr[i,k,m16*4..+3] summed over NCH chunk partials (L2-resident);
    // latency overlaps plane-0 DMA.
    const f4* __restrict__ xp4 = (const f4*)xr_part;
    f4 xr0 = {0.f,0.f,0.f,0.f};
    f4 xr1 = {0.f,0.f,0.f,0.f};
    f4 xr2 = {0.f,0.f,0.f,0.f};
    f4 xr3 = {0.f,0.f,0.f,0.f};
    #pragma unroll
    for (int c = 0; c < NCH; ++c) {
        const int base = (c * 512 + i) * 64;
        xr0 += xp4[base + 0 * 16 + m16];
        xr1 += xp4[base + 1 * 16 + m16];
        xr2 += xp4[base + 2 * 16 + m16];
        xr3 += xp4[base + 3 * 16 + m16];
    }

    f4 acc0 = {0.f,0.f,0.f,0.f};
    f4 acc1 = {0.f,0.f,0.f,0.f};
    f4 acc2 = {0.f,0.f,0.f,0.f};
    f4 acc3 = {0.f,0.f,0.f,0.f};

    const f4* buf0 = (const f4*)lds[0];
    const f4* buf1 = (const f4*)lds[1];
    const int ro = (w << 8) + lane;   // wave-contiguous ds_read_b128 pattern
                                      // f4 idx = w*256 + c2*64 + lane
                                      //        = l*16 + m16, l = w*16+c2*4+lq

    __syncthreads();                                    // plane 0 arrived

    // k=0: stage plane 1, compute plane 0
    #pragma unroll
    for (int p = 0; p < 4; ++p)
        gload_lds16(Wb + 1 * 4096 + p * 1024 + t * 4, &lds[1][p * 1024 + t * 4]);
    acc0 += buf0[ro +   0] * xr0;
    acc1 += buf0[ro +  64] * xr0;
    acc2 += buf0[ro + 128] * xr0;
    acc3 += buf0[ro + 192] * xr0;
    __syncthreads();                                    // plane 1 arrived, buf0 free

    // k=1: stage plane 2 -> buf0, compute plane 1
    #pragma unroll
    for (int p = 0; p < 4; ++p)
        gload_lds16(Wb + 2 * 4096 + p * 1024 + t * 4, &lds[0][p * 1024 + t * 4]);
    acc0 += buf1[ro +   0] * xr1;
    acc1 += buf1[ro +  64] * xr1;
    acc2 += buf1[ro + 128] * xr1;
    acc3 += buf1[ro + 192] * xr1;
    __syncthreads();                                    // plane 2 arrived, buf1 free

    // k=2: stage plane 3 -> buf1, compute plane 2
    #pragma unroll
    for (int p = 0; p < 4; ++p)
        gload_lds16(Wb + 3 * 4096 + p * 1024 + t * 4, &lds[1][p * 1024 + t * 4]);
    acc0 += buf0[ro +   0] * xr2;
    acc1 += buf0[ro +  64] * xr2;
    acc2 += buf0[ro + 128] * xr2;
    acc3 += buf0[ro + 192] * xr2;
    __syncthreads();                                    // plane 3 arrived

    // k=3: compute plane 3
    acc0 += buf1[ro +   0] * xr3;
    acc1 += buf1[ro +  64] * xr3;
    acc2 += buf1[ro + 128] * xr3;
    acc3 += buf1[ro + 192] * xr3;

    // reduce over m (16 lanes) and store; lane's element is l = w*16+c2*4+lq
    float p0 = acc0.x + acc0.y + acc0.z + acc0.w;
    float p1 = acc1.x + acc1.y + acc1.z + acc1.w;
    float p2 = acc2.x + acc2.y + acc2.z + acc2.w;
    float p3 = acc3.x + acc3.y + acc3.z + acc3.w;
    #pragma unroll
    for (int d = 1; d < 16; d <<= 1) {
        p0 += __shfl_xor(p0, d);
        p1 += __shfl_xor(p1, d);
        p2 += __shfl_xor(p2, d);
        p3 += __shfl_xor(p3, d);
    }
    if (m16 == 0) {
        const int lbase = b * 64 + (w << 4) + lq;
        y[lbase +  0] = p0;
        y[lbase +  4] = p1;
        y[lbase +  8] = p2;
        y[lbase + 12] = p3;
    }
}

extern "C" void kernel_launch(void* const* d_in, const int* in_sizes, int n_in,
                              void* d_out, int out_size, void* d_ws, size_t ws_size,
                              hipStream_t stream) {
    const float* x  = (const float*)d_in[0];   // 131072
    const float* Ci = (const float*)d_in[1];   // 512*4*512*4
    const float* Wi = (const float*)d_in[2];   // 512*4*4*64*64
    float* y  = (float*)d_out;                 // 512*4*64
    float* xr = (float*)d_ws;                  // NCH*512*256 floats = 4 MiB

    route_kernel<<<dim3(128, NCH), 256, 0, stream>>>(x, Ci, xr);
    transform_kernel<<<2048, 256, 0, stream>>>(Wi, xr, y);
}

// Round 5
// 225.285 us; speedup vs baseline: 1.0103x; 1.0103x over previous
//
#include <hip/hip_runtime.h>

// ScRRAMBLe capsule layer, R5: lockstep grid-stride streaming transform.
//
// R0-R4 evidence: every per-block-chunk Wi reader (burst, hoisted-NT, DMA
// double-buffer) caps at ~2 TB/s, while lockstep streamers (harness fill
// 6.9 TB/s, m13 copy 6.29 TB/s) run 3x faster. Theory: per-block chunking
// spreads the in-flight window over all 134 MB -> DRAM page thrash; lockstep
// grid-stride keeps a dense 4 MB instantaneous window -> page hits.
// Transform is now a pure streamer: idx = it*nthreads + tid, 16-lane
// shfl-reduce, atomicAdd into zeroed y.

typedef float f4 __attribute__((ext_vector_type(4)));

#define NCH 8   // ij chunks for routing kernel

// ---------------- Kernel A: routing einsum ---------------------------------
// grid (128 i-quads, NCH); block 256. Partials -> ws[0 .. 4MB).
__global__ __launch_bounds__(256) void route_kernel(
    const float* __restrict__ x,
    const float* __restrict__ Ci,
    float* __restrict__ xr_part)
{
    const int iq  = blockIdx.x;
    const int c   = blockIdx.y;
    const int t   = threadIdx.x;
    const int il  = t >> 6;
    const int g   = (t >> 4) & 3;
    const int mq4 = t & 15;
    const int i   = (iq << 2) + il;

    const f4* __restrict__ Ci4 = (const f4*)Ci;
    const f4* __restrict__ x4  = (const f4*)x;

    __shared__ f4 part[1024];

    f4 a0 = {0.f,0.f,0.f,0.f};
    f4 a1 = {0.f,0.f,0.f,0.f};
    f4 a2 = {0.f,0.f,0.f,0.f};
    f4 a3 = {0.f,0.f,0.f,0.f};

    const int ijpc = 2048 / NCH;      // 256
    const int sub  = ijpc >> 2;       // 64 per g-subgroup
    const int base = c * ijpc + g * sub;
    #pragma unroll 4
    for (int it = 0; it < sub; ++it) {
        const int ij = base + it;
        const f4 c4 = Ci4[ij * 512 + i];      // Ci[ij, i, 0:4]
        const f4 xv = x4[(ij << 4) + mq4];    // x[ij, 4*mq4 .. +3]
        a0 += c4.x * xv;
        a1 += c4.y * xv;
        a2 += c4.z * xv;
        a3 += c4.w * xv;
    }

    const int pb = ((g << 2) + il) << 2;
    part[(pb + 0) * 16 + mq4] = a0;
    part[(pb + 1) * 16 + mq4] = a1;
    part[(pb + 2) * 16 + mq4] = a2;
    part[(pb + 3) * 16 + mq4] = a3;
    __syncthreads();

    const int il2 = t >> 6;
    const int r   = (t >> 4) & 3;
    const int mm  = t & 15;
    f4 s = {0.f,0.f,0.f,0.f};
    #pragma unroll
    for (int gg = 0; gg < 4; ++gg)
        s += part[(((gg << 2) + il2) * 4 + r) * 16 + mm];

    f4* __restrict__ xp4 = (f4*)xr_part;
    xp4[(c * 512 + (iq << 2) + il2) * 64 + r * 16 + mm] = s;
}

// ---------------- Kernel A2: reduce chunk partials -> final xr -------------
// 32768 f4 elements; 128 blocks x 256.
__global__ __launch_bounds__(256) void reduce_xr_kernel(
    const float* __restrict__ xr_part,
    float* __restrict__ xr)
{
    const int t = blockIdx.x * 256 + threadIdx.x;   // f4 idx
    const f4* __restrict__ p4 = (const f4*)xr_part;
    f4 s = {0.f,0.f,0.f,0.f};
    #pragma unroll
    for (int c = 0; c < NCH; ++c) s += p4[c * 32768 + t];
    ((f4*)xr)[t] = s;
}

// ---------------- Kernel B: lockstep streaming transform -------------------
// 1024 blocks x 256 threads = 262144 threads, 32 iterations of f4.
// Wi f4 layout: idx = ((b*4 + k)*64 + l)*16 + m16, b = i*4+j.
__global__ __launch_bounds__(256) void transform_stream(
    const float* __restrict__ Wi,
    const float* __restrict__ xr,
    float* __restrict__ y)
{
    const int tid  = blockIdx.x * 256 + threadIdx.x;
    const int m16  = threadIdx.x & 15;

    const f4* __restrict__ W4  = (const f4*)Wi;
    const f4* __restrict__ xr4 = (const f4*)xr;

    #pragma unroll 4
    for (int it = 0; it < 32; ++it) {
        const int idx = it * 262144 + tid;    // f4 index < 2^23
        const f4 w = W4[idx];                 // wave: contiguous 1 KB;
                                              // grid: dense 4 MB window
        const int row = idx >> 4;             // (b*4+k)*64 + l
        const int i   = row >> 10;            // input capsule for xr
        const int k   = (row >> 6) & 3;
        const f4 xv = xr4[i * 64 + k * 16 + m16];   // L2-hot
        const f4 s4 = w * xv;
        float p = s4.x + s4.y + s4.z + s4.w;
        p += __shfl_xor(p, 1);
        p += __shfl_xor(p, 2);
        p += __shfl_xor(p, 4);
        p += __shfl_xor(p, 8);
        if (m16 == 0) {
            const int yi = ((row >> 8) << 6) | (row & 63);   // b*64 + l
            atomicAdd(&y[yi], p);
        }
    }
}

extern "C" void kernel_launch(void* const* d_in, const int* in_sizes, int n_in,
                              void* d_out, int out_size, void* d_ws, size_t ws_size,
                              hipStream_t stream) {
    const float* x  = (const float*)d_in[0];   // 131072
    const float* Ci = (const float*)d_in[1];   // 512*4*512*4
    const float* Wi = (const float*)d_in[2];   // 512*4*4*64*64
    float* y       = (float*)d_out;            // 512*4*64
    float* xr_part = (float*)d_ws;                         // NCH*512*256 f = 4 MiB
    float* xr      = (float*)d_ws + NCH * 512 * 256;       // 512*256 f = 512 KiB

    hipMemsetAsync(y, 0, (size_t)out_size * sizeof(float), stream);
    route_kernel<<<dim3(128, NCH), 256, 0, stream>>>(x, Ci, xr_part);
    reduce_xr_kernel<<<128, 256, 0, stream>>>(xr_part, xr);
    transform_stream<<<1024, 256, 0, stream>>>(Wi, xr, y);
}